// Round 1
// baseline (718.576 us; speedup 1.0000x reference)
//
#include <hip/hip_runtime.h>
#include <cstddef>

// Problem constants (from reference)
#define N0 200000
#define N1 50000
#define N2 10000
#define E0 800000
#define E1 160000
// feature dims: IN=H1=H2=256, EMB=128. K is always 256.

typedef short bf16x8 __attribute__((ext_vector_type(8)));            // 8 bf16 = 4 VGPRs
typedef float f32x4 __attribute__((ext_vector_type(4)));
typedef unsigned short us8 __attribute__((ext_vector_type(8)));      // 8 bf16 = 16 B

__device__ __forceinline__ unsigned short f2bf(float f) {
    unsigned int u = __float_as_uint(f);
    unsigned int r = (u + 0x7FFF + ((u >> 16) & 1)) >> 16;   // RNE
    return (unsigned short)r;
}
__device__ __forceinline__ float bf2f(unsigned short s) {
    return __uint_as_float(((unsigned int)s) << 16);
}

// async global->LDS, 16B per lane. lds dst must be the WAVE-UNIFORM base;
// HW writes lane i's 16B at base + i*16. global src IS per-lane.
__device__ __forceinline__ void gload_lds16(const void* g, void* l) {
    __builtin_amdgcn_global_load_lds(
        (const __attribute__((address_space(1))) unsigned int*)g,
        (__attribute__((address_space(3))) unsigned int*)l, 16, 0, 0);
}

// ---------------- fused weight pre-pack: W [K][N] fp32 -> MFMA B-fragment bf16 ----------------
// tile = (ct,s): lane holds B[k = s*32 + (lane>>4)*8 + j][n = ct*16 + (lane&15)], j=0..7
// Bp index: ((ct*8 + s)*64 + lane)*8
__global__ void pack_all(const float* __restrict__ W1, const float* __restrict__ W2,
                         const float* __restrict__ Wp,
                         unsigned short* __restrict__ W1p, unsigned short* __restrict__ W2p,
                         unsigned short* __restrict__ Wpp) {
    int tid = blockIdx.x * 256 + threadIdx.x;
    if (tid >= 320 * 64) return;           // 128 + 128 + 64 tiles
    int lane = tid & 63;
    int tile = tid >> 6;
    const float* W; unsigned short* Bp; int N; int lt;
    if (tile < 128)      { W = W1; Bp = W1p; N = 256; lt = tile; }
    else if (tile < 256) { W = W2; Bp = W2p; N = 256; lt = tile - 128; }
    else                 { W = Wp; Bp = Wpp; N = 128; lt = tile - 256; }
    int s  = lt & 7;
    int ct = lt >> 3;
    int col = ct * 16 + (lane & 15);
    int k0  = s * 32 + (lane >> 4) * 8;
    unsigned short* dst = Bp + ((size_t)lt * 64 + lane) * 8;
#pragma unroll
    for (int j = 0; j < 8; j++) dst[j] = f2bf(W[(size_t)(k0 + j) * N + col]);
}

// ---------------- fused degree count + per-edge rank (both layers) ----------------
__global__ void count_all(const int* __restrict__ src0, const int* __restrict__ dst0,
                          const int* __restrict__ src1, const int* __restrict__ dst1,
                          int* __restrict__ cnt_out0, int* __restrict__ cnt_in0,
                          int* __restrict__ cnt_out1, int* __restrict__ cnt_in1,
                          int* __restrict__ rank0, int* __restrict__ rank1) {
    int e = blockIdx.x * 256 + threadIdx.x;
    if (e < E0) {
        atomicAdd(&cnt_out0[src0[e]], 1);
        rank0[e] = atomicAdd(&cnt_in0[dst0[e]], 1);
    } else if (e < E0 + E1) {
        int f = e - E0;
        atomicAdd(&cnt_out1[src1[f]], 1);
        rank1[f] = atomicAdd(&cnt_in1[dst1[f]], 1);
    }
}

// ---------------- counts -> rsqrt(max(cnt,1)) scales ----------------
__global__ void scales_kernel(const int* __restrict__ cnt, float* __restrict__ rs, int n) {
    int i = blockIdx.x * 256 + threadIdx.x;
    if (i < n) rs[i] = rsqrtf((float)max(cnt[i], 1));
}

// ---------------- 2-block exclusive scan: block 0 -> rowptr0, block 1 -> rowptr1 ----------------
__global__ __launch_bounds__(1024) void scan2(const int* __restrict__ cnt_in0, int* __restrict__ rowptr0,
                                              const int* __restrict__ cnt_in1, int* __restrict__ rowptr1) {
    const int* cnt = blockIdx.x ? cnt_in1 : cnt_in0;
    int* rowptr    = blockIdx.x ? rowptr1 : rowptr0;
    const int n    = blockIdx.x ? N2 : N1;
    __shared__ int partial[1024];
    const int t = threadIdx.x;
    const int chunk = (n + 1023) / 1024;
    const int begin = t * chunk;
    const int end = min(begin + chunk, n);
    int sum = 0;
    for (int i = begin; i < end; i++) sum += cnt[i];
    partial[t] = sum;
    __syncthreads();
    for (int off = 1; off < 1024; off <<= 1) {
        int v = (t >= off) ? partial[t - off] : 0;
        __syncthreads();
        partial[t] += v;
        __syncthreads();
    }
    int run = partial[t] - sum;
    for (int i = begin; i < end; i++) {
        rowptr[i] = run;
        run += cnt[i];
    }
    if (t == 1023) rowptr[n] = partial[1023];
}

// ---------------- fused CSR fill (both layers) ----------------
__global__ void fill_all(const int* __restrict__ src0, const int* __restrict__ dst0,
                         const int* __restrict__ src1, const int* __restrict__ dst1,
                         const int* __restrict__ rank0, const int* __restrict__ rank1,
                         const int* __restrict__ rowptr0, const int* __restrict__ rowptr1,
                         int* __restrict__ csr0, int* __restrict__ csr1) {
    int e = blockIdx.x * 256 + threadIdx.x;
    if (e < E0) {
        csr0[rowptr0[dst0[e]] + rank0[e]] = src0[e];
    } else if (e < E0 + E1) {
        int f = e - E0;
        csr1[rowptr1[dst1[f]] + rank1[f]] = src1[f];
    }
}

// ---------------- bf16 MFMA GEMM, LDS-staged B + 4x register-blocked M ----------------
// block = 256 thr = 4 waves in a 2x2 (row x col) grid.
// block tile = (2*MREP*16) rows x N cols; wave tile = MREP*16 rows x (NTT/2)*16 cols.
// B is staged once per block into LDS (two K-phases of 4 k-steps = NTT*4 x 1KB tiles),
// via global_load_lds: one instruction copies exactly one (ct,s) fragment tile
// (lane's 16B contiguous in the prepack -> linear LDS, conflict-free b128 reads).
// Each B fragment feeds MREP MFMAs from registers -> B global traffic /= (waves/block * MREP).
// A: direct per-lane global loads (each element read once per block), fp32->bf16 in-register.
template <int MREP, int NTT, bool AF32, bool OBF16>
__global__ __launch_bounds__(256, 2) void gemm_mfma(const void* __restrict__ A_,
                                                    const unsigned short* __restrict__ Bp,
                                                    const float* __restrict__ rs,
                                                    const float* __restrict__ bias,
                                                    void* __restrict__ C_, int M, int N) {
    constexpr int NT = NTT / 2;                   // col-tiles per wave
    const int lane = threadIdx.x & 63;
    const int wid  = threadIdx.x >> 6;            // 0..3
    const int wr   = wid >> 1;                    // wave row 0..1
    const int wc   = wid & 1;                     // wave col 0..1
    const int lm   = lane & 15;
    const int quad = lane >> 4;                   // 0..3
    const int rowBlk = blockIdx.x * (2 * MREP * 16);

    __shared__ unsigned short Blds[NTT * 2048];   // NTT*4 tiles x 1KB (64KB for N=256)

    f32x4 acc[MREP][NT];
#pragma unroll
    for (int m = 0; m < MREP; m++)
#pragma unroll
        for (int ct = 0; ct < NT; ct++) acc[m][ct] = (f32x4){0.f, 0.f, 0.f, 0.f};

    // per-mrep A row pointers (clamped for the tail block)
    const float* aF[MREP];
    const unsigned short* aB[MREP];
#pragma unroll
    for (int m = 0; m < MREP; m++) {
        int r = min(rowBlk + wr * (MREP * 16) + m * 16 + lm, M - 1);
        if (AF32) aF[m] = (const float*)A_ + (size_t)r * 256 + quad * 8;
        else      aB[m] = (const unsigned short*)A_ + (size_t)r * 256 + quad * 8;
    }

#pragma unroll
    for (int p = 0; p < 2; p++) {                 // two K-phases of 128 (4 k-steps each)
        if (p) __syncthreads();                   // phase-0 compute done before overwrite
        // stage NTT*4 tiles; each wave stages NTT of them (1 tile per instruction)
#pragma unroll
        for (int t = 0; t < NTT; t++) {
            int tt = wid * NTT + t;               // tile id: tt = ct*4 + sl
            int ct = tt >> 2;
            int s  = p * 4 + (tt & 3);
            gload_lds16(Bp + (((size_t)ct * 8 + s) * 64 + lane) * 8,
                        &Blds[(size_t)tt * 512]);
        }
        __syncthreads();                          // compiler drains vmcnt before s_barrier

#pragma unroll
        for (int sl = 0; sl < 4; sl++) {
            const int s = p * 4 + sl;
            bf16x8 af[MREP];
#pragma unroll
            for (int m = 0; m < MREP; m++) {
                if (AF32) {
                    float4 x = *(const float4*)(aF[m] + s * 32);
                    float4 y = *(const float4*)(aF[m] + s * 32 + 4);
                    union { unsigned short u[8]; bf16x8 v; } a;
                    a.u[0] = f2bf(x.x); a.u[1] = f2bf(x.y); a.u[2] = f2bf(x.z); a.u[3] = f2bf(x.w);
                    a.u[4] = f2bf(y.x); a.u[5] = f2bf(y.y); a.u[6] = f2bf(y.z); a.u[7] = f2bf(y.w);
                    af[m] = a.v;
                } else {
                    af[m] = *(const bf16x8*)(aB[m] + s * 32);
                }
            }
#pragma unroll
            for (int ct = 0; ct < NT; ct++) {
                int ctg = wc * NT + ct;
                bf16x8 bfrag = *(const bf16x8*)&Blds[((size_t)(ctg * 4 + sl)) * 512 + lane * 8];
#pragma unroll
                for (int m = 0; m < MREP; m++)
                    acc[m][ct] = __builtin_amdgcn_mfma_f32_16x16x32_bf16(af[m], bfrag, acc[m][ct], 0, 0, 0);
            }
        }
    }

    // epilogue: C layout col=lane&15, row=quad*4+i (per 16x16 fragment)
#pragma unroll
    for (int m = 0; m < MREP; m++) {
        int rowBase = rowBlk + wr * (MREP * 16) + m * 16;
        f32x4 rsv = (f32x4){1.f, 1.f, 1.f, 1.f};
        if (rs) rsv = *(const f32x4*)(rs + rowBase + quad * 4);   // OOB rows read ws garbage, never stored
#pragma unroll
        for (int ct = 0; ct < NT; ct++) {
            int col = wc * (NT * 16) + ct * 16 + lm;
            float bv = bias ? bias[col] : 0.0f;
#pragma unroll
            for (int i = 0; i < 4; i++) {
                int row = rowBase + quad * 4 + i;
                if (row < M) {
                    float v = acc[m][ct][i] * rsv[i] + bv;
                    if (OBF16) ((unsigned short*)C_)[(size_t)row * N + col] = f2bf(v);
                    else       ((float*)C_)[(size_t)row * N + col] = v;
                }
            }
        }
    }
}

// ---------------- gather over pre-scaled bf16 rows (split-lane, 16 B/lane) ----------------
// one wave per dst row; lanes 0-31 and 32-63 process different edges of the same row.
// lane covers cols (lane&31)*8 .. +7; halves combined by shfl_xor(32) at the end.
__global__ __launch_bounds__(256) void gather_bf16(const unsigned short* __restrict__ Y,
                                                   const int* __restrict__ rowptr,
                                                   const int* __restrict__ csr,
                                                   const float* __restrict__ rs_dst,
                                                   const float* __restrict__ bias,
                                                   unsigned short* __restrict__ outb, int n_dst) {
    int w    = (blockIdx.x * 256 + threadIdx.x) >> 6;
    int lane = threadIdx.x & 63;
    if (w >= n_dst) return;
    int half = lane >> 5;
    int l32  = lane & 31;
    int e   = rowptr[w];
    int end = rowptr[w + 1];
    float acc[8] = {0.f, 0.f, 0.f, 0.f, 0.f, 0.f, 0.f, 0.f};
    // main: 8 edges per iteration (4 per half, 4 independent 16B loads in flight)
    for (; e + 7 < end; e += 8) {
        int s0 = csr[e + half];
        int s1 = csr[e + 2 + half];
        int s2 = csr[e + 4 + half];
        int s3 = csr[e + 6 + half];
        us8 v0 = *(const us8*)(Y + (size_t)s0 * 256 + l32 * 8);
        us8 v1 = *(const us8*)(Y + (size_t)s1 * 256 + l32 * 8);
        us8 v2 = *(const us8*)(Y + (size_t)s2 * 256 + l32 * 8);
        us8 v3 = *(const us8*)(Y + (size_t)s3 * 256 + l32 * 8);
#pragma unroll
        for (int j = 0; j < 8; j++)
            acc[j] += (bf2f(v0[j]) + bf2f(v1[j])) + (bf2f(v2[j]) + bf2f(v3[j]));
    }
    // pairs: 2 edges per iteration (both halves in-bounds)
    for (; e + 1 < end; e += 2) {
        int s0 = csr[e + half];
        us8 v0 = *(const us8*)(Y + (size_t)s0 * 256 + l32 * 8);
#pragma unroll
        for (int j = 0; j < 8; j++) acc[j] += bf2f(v0[j]);
    }
    // final odd edge: half 0 only
    if (e < end && half == 0) {
        int s0 = csr[e];
        us8 v0 = *(const us8*)(Y + (size_t)s0 * 256 + l32 * 8);
#pragma unroll
        for (int j = 0; j < 8; j++) acc[j] += bf2f(v0[j]);
    }
    // combine halves
#pragma unroll
    for (int j = 0; j < 8; j++) acc[j] += __shfl_xor(acc[j], 32);
    if (half == 0) {
        float sd = rs_dst[w];
        f32x4 ba = *(const f32x4*)(bias + l32 * 8);
        f32x4 bb = *(const f32x4*)(bias + l32 * 8 + 4);
        us8 o;
        o[0] = f2bf(acc[0] * sd + ba[0]);
        o[1] = f2bf(acc[1] * sd + ba[1]);
        o[2] = f2bf(acc[2] * sd + ba[2]);
        o[3] = f2bf(acc[3] * sd + ba[3]);
        o[4] = f2bf(acc[4] * sd + bb[0]);
        o[5] = f2bf(acc[5] * sd + bb[1]);
        o[6] = f2bf(acc[6] * sd + bb[2]);
        o[7] = f2bf(acc[7] * sd + bb[3]);
        *(us8*)(outb + (size_t)w * 256 + l32 * 8) = o;
    }
}

extern "C" void kernel_launch(void* const* d_in, const int* in_sizes, int n_in,
                              void* d_out, int out_size, void* d_ws, size_t ws_size,
                              hipStream_t stream) {
    const float* h    = (const float*)d_in[0];
    const int*   src0 = (const int*)d_in[1];
    const int*   dst0 = (const int*)d_in[2];
    const int*   src1 = (const int*)d_in[3];
    const int*   dst1 = (const int*)d_in[4];
    const float* W1   = (const float*)d_in[5];
    const float* b1   = (const float*)d_in[6];
    const float* W2   = (const float*)d_in[7];
    const float* b2   = (const float*)d_in[8];
    const float* Wp   = (const float*)d_in[9];
    const float* bp   = (const float*)d_in[10];
    float* out = (float*)d_out;

    // ---------------- workspace layout (with liveness-based aliasing) ----------------
    int* ib = (int*)d_ws;
    int* cnt_out0 = ib;                      // N0            [live: count..scales]
    int* cnt_in0  = cnt_out0 + N0;           // N1
    int* cnt_out1 = cnt_in0 + N1;            // N1
    int* cnt_in1  = cnt_out1 + N1;           // N2   (counts contiguous: 310000)
    int* rowptr0  = ib + 310000;             // N1+1          [live: scan..gather0]
    int* rowptr1  = ib + 360001;             // N2+1
    int* csr0     = ib + 370004;             // E0            [live: fill..gather0]
    int* csr1     = ib + 1170004;            // E1            -> ints end at 1,330,004
    float* fb = (float*)(ib + 1330004);
    float* rs_out0 = fb;                     // N0   (same order as counts)
    float* rs_in0  = fb + 200000;            // N1
    float* rs_out1 = fb + 250000;            // N1
    float* rs_in1  = fb + 300000;            // N2   (scales contiguous: 310000)
    unsigned short* wpk = (unsigned short*)(fb + 310000);
    unsigned short* W1p = wpk;               // 256*256
    unsigned short* W2p = wpk + 65536;       // 256*256
    unsigned short* Wpp = wpk + 131072;      // 256*128  -> 163840 ushorts
    // big aliased region R (102.4 MB): rank (dead before gemm1) / Y1 (dead after gather0)
    //                                  / {Y2, h2} (born at gemm2)
    unsigned short* R   = wpk + 163840;
    int* rank0 = (int*)R;                    // E0   [live: count..fill]
    int* rank1 = rank0 + E0;                 // E1
    unsigned short* Y1  = R;                 // N0*256 bf16   [live: gemm1..gather0]
    unsigned short* Y2  = R;                 // N1*256 bf16   [live: gemm2..gather1]
    unsigned short* h2b = R + (size_t)N1 * 256;  // N2*256 bf16 [live: gather1..gemmp]
    unsigned short* h1b = R + (size_t)N0 * 256;  // N1*256 bf16 [live: gather0..gemm2]

    // 1. zero count region (1.24 MB)
    hipMemsetAsync(cnt_out0, 0, (size_t)310000 * sizeof(int), stream);

    // 2. pack all three weight matrices into MFMA B-fragment layout
    pack_all<<<80, 256, 0, stream>>>(W1, W2, Wp, W1p, W2p, Wpp);

    // 3. degree counts + ranks (both layers, one dispatch)
    count_all<<<(E0 + E1 + 255) / 256, 256, 0, stream>>>(src0, dst0, src1, dst1,
                                                         cnt_out0, cnt_in0, cnt_out1, cnt_in1,
                                                         rank0, rank1);

    // 4. scales = rsqrt(max(cnt,1)) for all 4 arrays
    scales_kernel<<<(310000 + 255) / 256, 256, 0, stream>>>(cnt_out0, rs_out0, 310000);

    // 5. rowptrs (both layers, one dispatch)
    scan2<<<2, 1024, 0, stream>>>(cnt_in0, rowptr0, cnt_in1, rowptr1);

    // 6. CSR fill (both layers, one dispatch)
    fill_all<<<(E0 + E1 + 255) / 256, 256, 0, stream>>>(src0, dst0, src1, dst1,
                                                        rank0, rank1, rowptr0, rowptr1, csr0, csr1);

    // 7. Y1 = (h @ W1) * rs_out0[row]   [200000 x 256] bf16, pre-scaled
    //    128-row blocks, LDS-staged B, 4x M register blocking
    gemm_mfma<4, 16, true, true><<<(N0 + 127) / 128, 256, 0, stream>>>(h, W1p, rs_out0, nullptr, Y1, N0, 256);

    // 8. h1 = bf16( sum_{src} Y1[src] * rs_in0[dst] + b1 )   [50000 x 256]
    gather_bf16<<<(N1 + 3) / 4, 256, 0, stream>>>(Y1, rowptr0, csr0, rs_in0, b1, h1b, N1);

    // 9. Y2 = (h1 @ W2) * rs_out1[row]  [50000 x 256] bf16
    gemm_mfma<4, 16, false, true><<<(N1 + 127) / 128, 256, 0, stream>>>(h1b, W2p, rs_out1, nullptr, Y2, N1, 256);

    // 10. h2 = bf16( sum Y2[src] * rs_in1[dst] + b2 )   [10000 x 256]
    gather_bf16<<<(N2 + 3) / 4, 256, 0, stream>>>(Y2, rowptr1, csr1, rs_in1, b2, h2b, N2);

    // 11. out = h2 @ Wp + bp   [10000 x 128] fp32  (64-row blocks: 157 blocks for grid fill)
    gemm_mfma<2, 8, false, false><<<(N2 + 63) / 64, 256, 0, stream>>>(h2b, Wpp, nullptr, bp, out, N2, 128);
}

// Round 4
// 635.944 us; speedup vs baseline: 1.1299x; 1.1299x over previous
//
#include <hip/hip_runtime.h>
#include <cstddef>

// Problem constants (from reference)
#define N0 200000
#define N1 50000
#define N2 10000
#define E0 800000
#define E1 160000
// feature dims: IN=H1=H2=256, EMB=128. K is always 256.
//
// Restructured pipeline (aggregation commutes with @W because per-row scales are scalars):
//   a0  = rs_in0[dst] * sum_{src} rs_out0[src] * h[src]          (gather_f32, fp32 in, bf16 out)
//   t1  = bf16( (a0 @ W1 + b1) * rs_out1[row] )                  (gemm, M=N1)
//   a1  = rs_in1[dst] * sum_{src} t1[src]                        (gather_bf16, no bias)
//   h2  = bf16( a1 @ W2 + b2 )                                   (gemm, M=N2)
//   out = h2 @ Wp + bp                                           (gemm, M=N2, fp32 out)
// This removes the M=200000 GEMM (the 186us latency-bound dispatch) entirely.

typedef short bf16x8 __attribute__((ext_vector_type(8)));            // 8 bf16 = 4 VGPRs
typedef float f32x4 __attribute__((ext_vector_type(4)));
typedef unsigned short us8 __attribute__((ext_vector_type(8)));      // 8 bf16 = 16 B

__device__ __forceinline__ unsigned short f2bf(float f) {
    unsigned int u = __float_as_uint(f);
    unsigned int r = (u + 0x7FFF + ((u >> 16) & 1)) >> 16;   // RNE
    return (unsigned short)r;
}
__device__ __forceinline__ float bf2f(unsigned short s) {
    return __uint_as_float(((unsigned int)s) << 16);
}

// ---------------- fused weight pre-pack: W [K][N] fp32 -> MFMA B-fragment bf16 ----------------
// tile = (ct,s): lane holds B[k = s*32 + (lane>>4)*8 + j][n = ct*16 + (lane&15)], j=0..7
// Bp index: ((ct*8 + s)*64 + lane)*8
__global__ void pack_all(const float* __restrict__ W1, const float* __restrict__ W2,
                         const float* __restrict__ Wp,
                         unsigned short* __restrict__ W1p, unsigned short* __restrict__ W2p,
                         unsigned short* __restrict__ Wpp) {
    int tid = blockIdx.x * 256 + threadIdx.x;
    if (tid >= 320 * 64) return;           // 128 + 128 + 64 tiles
    int lane = tid & 63;
    int tile = tid >> 6;
    const float* W; unsigned short* Bp; int N; int lt;
    if (tile < 128)      { W = W1; Bp = W1p; N = 256; lt = tile; }
    else if (tile < 256) { W = W2; Bp = W2p; N = 256; lt = tile - 128; }
    else                 { W = Wp; Bp = Wpp; N = 128; lt = tile - 256; }
    int s  = lt & 7;
    int ct = lt >> 3;
    int col = ct * 16 + (lane & 15);
    int k0  = s * 32 + (lane >> 4) * 8;
    unsigned short* dst = Bp + ((size_t)lt * 64 + lane) * 8;
#pragma unroll
    for (int j = 0; j < 8; j++) dst[j] = f2bf(W[(size_t)(k0 + j) * N + col]);
}

// ---------------- fused degree count + per-edge rank (both layers) ----------------
__global__ void count_all(const int* __restrict__ src0, const int* __restrict__ dst0,
                          const int* __restrict__ src1, const int* __restrict__ dst1,
                          int* __restrict__ cnt_out0, int* __restrict__ cnt_in0,
                          int* __restrict__ cnt_out1, int* __restrict__ cnt_in1,
                          int* __restrict__ rank0, int* __restrict__ rank1) {
    int e = blockIdx.x * 256 + threadIdx.x;
    if (e < E0) {
        atomicAdd(&cnt_out0[src0[e]], 1);
        rank0[e] = atomicAdd(&cnt_in0[dst0[e]], 1);
    } else if (e < E0 + E1) {
        int f = e - E0;
        atomicAdd(&cnt_out1[src1[f]], 1);
        rank1[f] = atomicAdd(&cnt_in1[dst1[f]], 1);
    }
}

// ---------------- counts -> rsqrt(max(cnt,1)) scales ----------------
__global__ void scales_kernel(const int* __restrict__ cnt, float* __restrict__ rs, int n) {
    int i = blockIdx.x * 256 + threadIdx.x;
    if (i < n) rs[i] = rsqrtf((float)max(cnt[i], 1));
}

// ---------------- 2-block exclusive scan: block 0 -> rowptr0, block 1 -> rowptr1 ----------------
__global__ __launch_bounds__(1024) void scan2(const int* __restrict__ cnt_in0, int* __restrict__ rowptr0,
                                              const int* __restrict__ cnt_in1, int* __restrict__ rowptr1) {
    const int* cnt = blockIdx.x ? cnt_in1 : cnt_in0;
    int* rowptr    = blockIdx.x ? rowptr1 : rowptr0;
    const int n    = blockIdx.x ? N2 : N1;
    __shared__ int partial[1024];
    const int t = threadIdx.x;
    const int chunk = (n + 1023) / 1024;
    const int begin = t * chunk;
    const int end = min(begin + chunk, n);
    int sum = 0;
    for (int i = begin; i < end; i++) sum += cnt[i];
    partial[t] = sum;
    __syncthreads();
    for (int off = 1; off < 1024; off <<= 1) {
        int v = (t >= off) ? partial[t - off] : 0;
        __syncthreads();
        partial[t] += v;
        __syncthreads();
    }
    int run = partial[t] - sum;
    for (int i = begin; i < end; i++) {
        rowptr[i] = run;
        run += cnt[i];
    }
    if (t == 1023) rowptr[n] = partial[1023];
}

// ---------------- fused CSR fill (both layers) ----------------
__global__ void fill_all(const int* __restrict__ src0, const int* __restrict__ dst0,
                         const int* __restrict__ src1, const int* __restrict__ dst1,
                         const int* __restrict__ rank0, const int* __restrict__ rank1,
                         const int* __restrict__ rowptr0, const int* __restrict__ rowptr1,
                         int* __restrict__ csr0, int* __restrict__ csr1) {
    int e = blockIdx.x * 256 + threadIdx.x;
    if (e < E0) {
        csr0[rowptr0[dst0[e]] + rank0[e]] = src0[e];
    } else if (e < E0 + E1) {
        int f = e - E0;
        csr1[rowptr1[dst1[f]] + rank1[f]] = src1[f];
    }
}

// ---------------- bf16 MFMA GEMM: wave = 16 rows x full N (round-0 structure) ----------------
// block = 256 thr = 4 waves = 64 distinct rows. B is small + L2-resident; each wave streams it.
// BS: epilogue order. BS=true:  v = (acc + bias[col]) * rs[row]   (bias-then-scale)
//                     BS=false: v = acc * rs[row] + bias[col]     (scale-then-bias)
template <int NT, bool AF32, bool OBF16, bool BS>
__global__ __launch_bounds__(256) void gemm_mfma(const void* __restrict__ A_,
                                                 const unsigned short* __restrict__ Bp,
                                                 const float* __restrict__ rs,
                                                 const float* __restrict__ bias,
                                                 void* __restrict__ C_, int M, int N) {
    const int lane = threadIdx.x & 63;
    const int wave = threadIdx.x >> 6;            // 0..3
    const int rowBase = blockIdx.x * 64 + wave * 16;
    const int lm = lane & 15;
    const int quad = lane >> 4;                   // 0..3

    f32x4 acc[NT];
#pragma unroll
    for (int ct = 0; ct < NT; ct++) acc[ct] = (f32x4){0.f, 0.f, 0.f, 0.f};

    const int rowA = min(rowBase + lm, M - 1);
    const float* af32 = (const float*)A_ + (size_t)rowA * 256 + quad * 8;
    const unsigned short* abf = (const unsigned short*)A_ + (size_t)rowA * 256 + quad * 8;

#pragma unroll 2
    for (int s = 0; s < 8; s++) {                 // K = 256, 32 per step
        bf16x8 afrag;
        if (AF32) {
            float4 x = *(const float4*)(af32 + s * 32);
            float4 y = *(const float4*)(af32 + s * 32 + 4);
            union { unsigned short u[8]; bf16x8 v; } af;
            af.u[0] = f2bf(x.x); af.u[1] = f2bf(x.y); af.u[2] = f2bf(x.z); af.u[3] = f2bf(x.w);
            af.u[4] = f2bf(y.x); af.u[5] = f2bf(y.y); af.u[6] = f2bf(y.z); af.u[7] = f2bf(y.w);
            afrag = af.v;
        } else {
            afrag = *(const bf16x8*)(abf + s * 32);
        }
#pragma unroll
        for (int ct = 0; ct < NT; ct++) {
            bf16x8 bfrag = *(const bf16x8*)(Bp + (((size_t)ct * 8 + s) * 64 + lane) * 8);
            acc[ct] = __builtin_amdgcn_mfma_f32_16x16x32_bf16(afrag, bfrag, acc[ct], 0, 0, 0);
        }
    }

    // epilogue: C layout col=lane&15, row=quad*4+i
    // rs index clamped to the last in-bounds 16B-aligned quad (M is a multiple of 4),
    // so tail blocks never read past rs[M-1]; clamped rows are never stored (row<M guard).
    f32x4 rsv = (f32x4){1.f, 1.f, 1.f, 1.f};
    if (rs) rsv = *(const f32x4*)(rs + min(rowBase + quad * 4, M - 4));
#pragma unroll
    for (int ct = 0; ct < NT; ct++) {
        int col = ct * 16 + lm;
        float bv = bias ? bias[col] : 0.0f;
#pragma unroll
        for (int i = 0; i < 4; i++) {
            int row = rowBase + quad * 4 + i;
            if (row < M) {
                float v = acc[ct][i];
                if (BS) { v = (v + bv) * rsv[i]; }
                else    { v = v * rsv[i] + bv; }
                if (OBF16) ((unsigned short*)C_)[(size_t)row * N + col] = f2bf(v);
                else       ((float*)C_)[(size_t)row * N + col] = v;
            }
        }
    }
}

// ---------------- layer-1 aggregation directly over fp32 h, per-edge src scaling ----------------
// one wave per dst row; halves (lanes 0-31 / 32-63) process alternating edges of the same row.
// lane covers cols (lane&31)*8 .. +7 (32B/lane); out = bf16( rs_dst[w] * sum rs_src[s]*H[s] ).
__global__ __launch_bounds__(256) void gather_f32(const float* __restrict__ H,
                                                  const float* __restrict__ rs_src,
                                                  const int* __restrict__ rowptr,
                                                  const int* __restrict__ csr,
                                                  const float* __restrict__ rs_dst,
                                                  unsigned short* __restrict__ outb, int n_dst) {
    int w    = (blockIdx.x * 256 + threadIdx.x) >> 6;
    int lane = threadIdx.x & 63;
    if (w >= n_dst) return;
    int half = lane >> 5;
    int l32  = lane & 31;
    int e   = rowptr[w];
    int end = rowptr[w + 1];
    float acc[8] = {0.f, 0.f, 0.f, 0.f, 0.f, 0.f, 0.f, 0.f};
    // main: 8 edges per iteration (4 per half, 8 independent 16B loads in flight)
    for (; e + 7 < end; e += 8) {
        int s0 = csr[e + half];
        int s1 = csr[e + 2 + half];
        int s2 = csr[e + 4 + half];
        int s3 = csr[e + 6 + half];
        float r0 = rs_src[s0], r1 = rs_src[s1], r2 = rs_src[s2], r3 = rs_src[s3];
        const float* p0 = H + (size_t)s0 * 256 + l32 * 8;
        const float* p1 = H + (size_t)s1 * 256 + l32 * 8;
        const float* p2 = H + (size_t)s2 * 256 + l32 * 8;
        const float* p3 = H + (size_t)s3 * 256 + l32 * 8;
        float4 x0 = *(const float4*)p0, y0 = *(const float4*)(p0 + 4);
        float4 x1 = *(const float4*)p1, y1 = *(const float4*)(p1 + 4);
        float4 x2 = *(const float4*)p2, y2 = *(const float4*)(p2 + 4);
        float4 x3 = *(const float4*)p3, y3 = *(const float4*)(p3 + 4);
        acc[0] += x0.x * r0 + x1.x * r1 + x2.x * r2 + x3.x * r3;
        acc[1] += x0.y * r0 + x1.y * r1 + x2.y * r2 + x3.y * r3;
        acc[2] += x0.z * r0 + x1.z * r1 + x2.z * r2 + x3.z * r3;
        acc[3] += x0.w * r0 + x1.w * r1 + x2.w * r2 + x3.w * r3;
        acc[4] += y0.x * r0 + y1.x * r1 + y2.x * r2 + y3.x * r3;
        acc[5] += y0.y * r0 + y1.y * r1 + y2.y * r2 + y3.y * r3;
        acc[6] += y0.z * r0 + y1.z * r1 + y2.z * r2 + y3.z * r3;
        acc[7] += y0.w * r0 + y1.w * r1 + y2.w * r2 + y3.w * r3;
    }
    // pairs: 2 edges per iteration (one per half)
    for (; e + 1 < end; e += 2) {
        int s0 = csr[e + half];
        float r0 = rs_src[s0];
        const float* p0 = H + (size_t)s0 * 256 + l32 * 8;
        float4 x0 = *(const float4*)p0, y0 = *(const float4*)(p0 + 4);
        acc[0] += x0.x * r0; acc[1] += x0.y * r0; acc[2] += x0.z * r0; acc[3] += x0.w * r0;
        acc[4] += y0.x * r0; acc[5] += y0.y * r0; acc[6] += y0.z * r0; acc[7] += y0.w * r0;
    }
    // final odd edge: half 0 only
    if (e < end && half == 0) {
        int s0 = csr[e];
        float r0 = rs_src[s0];
        const float* p0 = H + (size_t)s0 * 256 + l32 * 8;
        float4 x0 = *(const float4*)p0, y0 = *(const float4*)(p0 + 4);
        acc[0] += x0.x * r0; acc[1] += x0.y * r0; acc[2] += x0.z * r0; acc[3] += x0.w * r0;
        acc[4] += y0.x * r0; acc[5] += y0.y * r0; acc[6] += y0.z * r0; acc[7] += y0.w * r0;
    }
    // combine halves
#pragma unroll
    for (int j = 0; j < 8; j++) acc[j] += __shfl_xor(acc[j], 32);
    if (half == 0) {
        float sd = rs_dst[w];
        us8 o;
#pragma unroll
        for (int j = 0; j < 8; j++) o[j] = f2bf(acc[j] * sd);
        *(us8*)(outb + (size_t)w * 256 + l32 * 8) = o;
    }
}

// ---------------- gather over pre-scaled bf16 rows (split-lane, 16 B/lane) ----------------
// out = bf16( rs_dst[w] * sum Y[src] + (bias ? bias : 0) )
__global__ __launch_bounds__(256) void gather_bf16(const unsigned short* __restrict__ Y,
                                                   const int* __restrict__ rowptr,
                                                   const int* __restrict__ csr,
                                                   const float* __restrict__ rs_dst,
                                                   const float* __restrict__ bias,
                                                   unsigned short* __restrict__ outb, int n_dst) {
    int w    = (blockIdx.x * 256 + threadIdx.x) >> 6;
    int lane = threadIdx.x & 63;
    if (w >= n_dst) return;
    int half = lane >> 5;
    int l32  = lane & 31;
    int e   = rowptr[w];
    int end = rowptr[w + 1];
    float acc[8] = {0.f, 0.f, 0.f, 0.f, 0.f, 0.f, 0.f, 0.f};
    for (; e + 7 < end; e += 8) {
        int s0 = csr[e + half];
        int s1 = csr[e + 2 + half];
        int s2 = csr[e + 4 + half];
        int s3 = csr[e + 6 + half];
        us8 v0 = *(const us8*)(Y + (size_t)s0 * 256 + l32 * 8);
        us8 v1 = *(const us8*)(Y + (size_t)s1 * 256 + l32 * 8);
        us8 v2 = *(const us8*)(Y + (size_t)s2 * 256 + l32 * 8);
        us8 v3 = *(const us8*)(Y + (size_t)s3 * 256 + l32 * 8);
#pragma unroll
        for (int j = 0; j < 8; j++)
            acc[j] += (bf2f(v0[j]) + bf2f(v1[j])) + (bf2f(v2[j]) + bf2f(v3[j]));
    }
    for (; e + 1 < end; e += 2) {
        int s0 = csr[e + half];
        us8 v0 = *(const us8*)(Y + (size_t)s0 * 256 + l32 * 8);
#pragma unroll
        for (int j = 0; j < 8; j++) acc[j] += bf2f(v0[j]);
    }
    if (e < end && half == 0) {
        int s0 = csr[e];
        us8 v0 = *(const us8*)(Y + (size_t)s0 * 256 + l32 * 8);
#pragma unroll
        for (int j = 0; j < 8; j++) acc[j] += bf2f(v0[j]);
    }
#pragma unroll
    for (int j = 0; j < 8; j++) acc[j] += __shfl_xor(acc[j], 32);
    if (half == 0) {
        float sd = rs_dst[w];
        float bj[8] = {0.f, 0.f, 0.f, 0.f, 0.f, 0.f, 0.f, 0.f};
        if (bias) {
            f32x4 ba = *(const f32x4*)(bias + l32 * 8);
            f32x4 bb = *(const f32x4*)(bias + l32 * 8 + 4);
            bj[0] = ba[0]; bj[1] = ba[1]; bj[2] = ba[2]; bj[3] = ba[3];
            bj[4] = bb[0]; bj[5] = bb[1]; bj[6] = bb[2]; bj[7] = bb[3];
        }
        us8 o;
#pragma unroll
        for (int j = 0; j < 8; j++) o[j] = f2bf(acc[j] * sd + bj[j]);
        *(us8*)(outb + (size_t)w * 256 + l32 * 8) = o;
    }
}

extern "C" void kernel_launch(void* const* d_in, const int* in_sizes, int n_in,
                              void* d_out, int out_size, void* d_ws, size_t ws_size,
                              hipStream_t stream) {
    const float* h    = (const float*)d_in[0];
    const int*   src0 = (const int*)d_in[1];
    const int*   dst0 = (const int*)d_in[2];
    const int*   src1 = (const int*)d_in[3];
    const int*   dst1 = (const int*)d_in[4];
    const float* W1   = (const float*)d_in[5];
    const float* b1   = (const float*)d_in[6];
    const float* W2   = (const float*)d_in[7];
    const float* b2   = (const float*)d_in[8];
    const float* Wp   = (const float*)d_in[9];
    const float* bp   = (const float*)d_in[10];
    float* out = (float*)d_out;

    // ---------------- workspace layout (liveness-based aliasing, ~58 MB total) ----------------
    int* ib = (int*)d_ws;
    int* cnt_out0 = ib;                      // N0            [live: count..scales]
    int* cnt_in0  = cnt_out0 + N0;           // N1
    int* cnt_out1 = cnt_in0 + N1;            // N1
    int* cnt_in1  = cnt_out1 + N1;           // N2   (counts contiguous: 310000)
    int* rowptr0  = ib + 310000;             // N1+1          [live: scan..gather0]
    int* rowptr1  = ib + 360001;             // N2+1          [live: scan..gather1]
    int* csr0     = ib + 370004;             // E0            [live: fill..gather0]
    int* csr1     = ib + 1170004;            // E1            -> ints end at 1,330,004
    float* fb = (float*)(ib + 1330004);
    float* rs_out0 = fb;                     // N0   (same order as counts)
    float* rs_in0  = fb + 200000;            // N1
    float* rs_out1 = fb + 250000;            // N1
    float* rs_in1  = fb + 300000;            // N2   (scales contiguous: 310000)
    unsigned short* wpk = (unsigned short*)(fb + 310000);
    unsigned short* W1p = wpk;               // 256*256
    unsigned short* W2p = wpk + 65536;       // 256*256
    unsigned short* Wpp = wpk + 131072;      // 256*128  -> 163840 ushorts
    // region R1 (25.6 MB): rank (dead before gather0) / a0b [gather0..gemm1] / a1b [gather1..gemm2]
    unsigned short* R1  = wpk + 163840;
    int* rank0 = (int*)R1;                   // E0   [live: count..fill]
    int* rank1 = rank0 + E0;                 // E1
    unsigned short* a0b = R1;                // N1*256 bf16
    unsigned short* a1b = R1;                // N2*256 bf16 (a0b dead by gather1)
    // region R2 (25.6 MB): t1 [gemm1..gather1] / h2b [gemm2..gemmp]
    unsigned short* R2  = R1 + (size_t)N1 * 256;
    unsigned short* t1  = R2;                // N1*256 bf16
    unsigned short* h2b = R2;                // N2*256 bf16 (t1 dead by gemm2)

    // 1. zero count region (1.24 MB)
    hipMemsetAsync(cnt_out0, 0, (size_t)310000 * sizeof(int), stream);

    // 2. pack all three weight matrices into MFMA B-fragment layout
    pack_all<<<80, 256, 0, stream>>>(W1, W2, Wp, W1p, W2p, Wpp);

    // 3. degree counts + ranks (both layers, one dispatch)
    count_all<<<(E0 + E1 + 255) / 256, 256, 0, stream>>>(src0, dst0, src1, dst1,
                                                         cnt_out0, cnt_in0, cnt_out1, cnt_in1,
                                                         rank0, rank1);

    // 4. scales = rsqrt(max(cnt,1)) for all 4 arrays
    scales_kernel<<<(310000 + 255) / 256, 256, 0, stream>>>(cnt_out0, rs_out0, 310000);

    // 5. rowptrs (both layers, one dispatch)
    scan2<<<2, 1024, 0, stream>>>(cnt_in0, rowptr0, cnt_in1, rowptr1);

    // 6. CSR fill (both layers, one dispatch)
    fill_all<<<(E0 + E1 + 255) / 256, 256, 0, stream>>>(src0, dst0, src1, dst1,
                                                        rank0, rank1, rowptr0, rowptr1, csr0, csr1);

    // 7. a0 = bf16( rs_in0[dst] * sum rs_out0[src]*h[src] )   [50000 x 256]
    gather_f32<<<(N1 + 3) / 4, 256, 0, stream>>>(h, rs_out0, rowptr0, csr0, rs_in0, a0b, N1);

    // 8. t1 = bf16( (a0 @ W1 + b1) * rs_out1[row] )   [50000 x 256]
    gemm_mfma<16, false, true, true><<<(N1 + 63) / 64, 256, 0, stream>>>(a0b, W1p, rs_out1, b1, t1, N1, 256);

    // 9. a1 = bf16( rs_in1[dst] * sum t1[src] )   [10000 x 256]
    gather_bf16<<<(N2 + 3) / 4, 256, 0, stream>>>(t1, rowptr1, csr1, rs_in1, nullptr, a1b, N2);

    // 10. h2 = bf16( a1 @ W2 + b2 )   [10000 x 256]
    gemm_mfma<16, false, true, false><<<(N2 + 63) / 64, 256, 0, stream>>>(a1b, W2p, nullptr, b2, h2b, N2, 256);

    // 11. out = h2 @ Wp + bp   [10000 x 128] fp32
    gemm_mfma<8, false, false, false><<<(N2 + 63) / 64, 256, 0, stream>>>(h2b, Wpp, nullptr, bp, out, N2, 128);
}